// Round 8
// baseline (755.677 us; speedup 1.0000x reference)
//
#include <hip/hip_runtime.h>

#define N_ROWS 65536          // 16*4096
#define DIM    256
#define KCB    1024

// d_out layout (floats), in reference return order
#define Q_OFF    0
#define ENC_OFF  (N_ROWS * DIM)                  // 16777216
#define IDX_OFF  (ENC_OFF + N_ROWS * KCB)        // 83886080
#define LOSS_OFF (IDX_OFF + N_ROWS)              // 83951616

// scratch carved out of the encodings region (overwritten by final kernel)
#define ET_OFF   (ENC_OFF + 0)                   // 262144 f32: E^T
#define NRM_OFF  (ENC_OFF + 262144)              // 1024 f32: ||e||^2
#define IDXI_OFF (ENC_OFF + 263168)              // 65536 int: final argmin
#define PART_OFF (ENC_OFF + 328704)              // 16384 f32: fb list / loss partials
#define AMB_OFF  (ENC_OFF + 345088)              // [0]=cand cnt [1]=fb cnt; entries @+16
#define PMIN_OFF (ENC_OFF + 524288)              // 65536*16 float4 partial minima
#define A2_OFF   (ENC_OFF + 4718592)             // bf16 [65536][512] {hi|lo}
#define BST_OFF  (ENC_OFF + 21495808)            // bf16 [1024][512] {ehi|elo}

#define TAU 0.05f        // validated r6/r7; flags rows AND bounds candidate set
#define MAXCAND 20000    // entry cap (8 ints each, fits AMB region)
#define MAXFB   16000

typedef short  bf16x8 __attribute__((ext_vector_type(8)));
typedef float  f32x4  __attribute__((ext_vector_type(4)));
typedef unsigned short u16x8 __attribute__((ext_vector_type(8)));
#define AS1 __attribute__((address_space(1)))
#define AS3 __attribute__((address_space(3)))

__device__ inline unsigned short f2bf(float x) {
    unsigned u = __float_as_uint(x);
    return (unsigned short)((u + 0x7FFFu + ((u >> 16) & 1u)) >> 16);
}
__device__ inline float bf2f(unsigned short b) {
    return __uint_as_float(((unsigned)b) << 16);
}

// ---------------------------------------------------------------------------
// split X (f32) -> A2 [row][512] bf16: [0,256)=hi, [256,512)=lo
__global__ __launch_bounds__(256)
void vq_prep_a(const float* __restrict__ X, float* __restrict__ out) {
    unsigned short* A2 = (unsigned short*)(out + A2_OFF);
    int gid = blockIdx.x * 256 + threadIdx.x;
    int row = gid >> 5;
    int d0  = (gid & 31) * 8;
    const float* xp = X + (size_t)row * DIM + d0;
    float4 v0 = *(const float4*)xp;
    float4 v1 = *(const float4*)(xp + 4);
    float xv[8] = {v0.x, v0.y, v0.z, v0.w, v1.x, v1.y, v1.z, v1.w};
    u16x8 h, l;
#pragma unroll
    for (int i = 0; i < 8; ++i) {
        unsigned short hb = f2bf(xv[i]);
        h[i] = hb;
        l[i] = f2bf(xv[i] - bf2f(hb));
    }
    *(u16x8*)(A2 + (size_t)row * 512 + d0) = h;
    *(u16x8*)(A2 + (size_t)row * 512 + 256 + d0) = l;
}

// ---------------------------------------------------------------------------
// E -> ET [1024][256] f32, nrm [1024], B2 [1024][512] bf16 {hi|lo}
// nrm chain must stay identical to round-2 prep (rescore replicates bit-exact).
__global__ __launch_bounds__(64)
void vq_prep_b(const float* __restrict__ E, float* __restrict__ out) {
    float* ET  = out + ET_OFF;
    float* nrm = out + NRM_OFF;
    unsigned short* B2 = (unsigned short*)(out + BST_OFF);
    const int k = blockIdx.x, t = threadIdx.x;
    float v[4]; float s = 0.f;
    ushort4 hb, lb;
#pragma unroll
    for (int i = 0; i < 4; ++i) {
        float e = E[(size_t)(t * 4 + i) * KCB + k];
        v[i] = e; s += e * e;
        unsigned short h = f2bf(e);
        ((unsigned short*)&hb)[i] = h;
        ((unsigned short*)&lb)[i] = f2bf(e - bf2f(h));
    }
    *(float4*)(ET + (size_t)k * DIM + t * 4) = *(float4*)v;
    *(ushort4*)(B2 + (size_t)k * 512 + t * 4) = hb;
    *(ushort4*)(B2 + (size_t)k * 512 + 256 + t * 4) = lb;
#pragma unroll
    for (int off = 32; off >= 1; off >>= 1) s += __shfl_xor(s, off);
    if (t == 0) nrm[k] = s;
    if (k == 0 && t == 0) { int* a = (int*)(out + AMB_OFF); a[0] = 0; a[1] = 0; }
}

// ---------------------------------------------------------------------------
// MFMA distance GEMM (sim = x_hi.e_hi + x_hi.e_lo + x_lo.e_hi), 128x128 tile,
// XOR-swizzled LDS (pre-swizzled global src + swizzled ds_read).
// Epilogue: per-row top-2 WITH indices -> pmin[row][cb*2+wc] = {a,ia,b,ib}.
__global__ __launch_bounds__(256, 3)
void vq_gemm(float* __restrict__ out) {
    __shared__ short lds[24576];   // A @0B, Bhi @16384B, Blo @32768B
    const unsigned short* A2 = (const unsigned short*)(out + A2_OFF);
    const unsigned short* B2 = (const unsigned short*)(out + BST_OFF);
    const float* nrm = out + NRM_OFF;
    float4* pmin = (float4*)(out + PMIN_OFF);

    const int orig = blockIdx.x;
    const int mapped = (orig & 7) * 512 + (orig >> 3);   // XCD-contiguous
    const int rb = mapped >> 3, cb = mapped & 7;
    const int row0 = rb * 128, col0 = cb * 128;

    const int tid = threadIdx.x;
    const int lane = tid & 63, l15 = lane & 15, lhi = lane >> 4;
    const int w = tid >> 6, wr = w >> 1, wc = w & 1;
    const int swz = (l15 & 7) * 8;          // read-side XOR (shorts)

    f32x4 acc[4][4];
#pragma unroll
    for (int i = 0; i < 4; ++i)
#pragma unroll
        for (int j = 0; j < 4; ++j) acc[i][j] = (f32x4){0.f, 0.f, 0.f, 0.f};

    const int sr   = tid >> 3;
    const int sksw = ((tid & 7) ^ ((tid >> 3) & 7)) * 8;   // swizzled src col
    const int wofs = (tid & 192) * 16;

#define STAGE4(SRC, R0, KOFF, LDSB)                                           \
    _Pragma("unroll")                                                         \
    for (int i = 0; i < 4; ++i) {                                             \
        __builtin_amdgcn_global_load_lds(                                     \
            (const AS1 unsigned*)((SRC) + (size_t)((R0) + i * 32 + sr) * 512  \
                                  + (KOFF) + sksw),                           \
            (AS3 unsigned*)((char*)lds + (LDSB) + i * 4096 + wofs), 16, 0, 0);\
    }

    // pass 1: acc += hi·ehi + hi·elo  (bh/bl loads split around MFMA groups)
    for (int kr = 0; kr < 4; ++kr) {
        __syncthreads();
        STAGE4(A2, row0, kr * 64, 0);
        STAGE4(B2, col0, kr * 64, 16384);
        STAGE4(B2, col0, 256 + kr * 64, 32768);
        asm volatile("s_waitcnt vmcnt(0)" ::: "memory");
        __syncthreads();
#pragma unroll
        for (int kk = 0; kk < 2; ++kk) {
            const int cofs = (kk * 32 + lhi * 8) ^ swz;
            bf16x8 af[4], bf[4];
#pragma unroll
            for (int mi = 0; mi < 4; ++mi)
                af[mi] = *(const bf16x8*)&lds[(wr * 64 + mi * 16 + l15) * 64 + cofs];
#pragma unroll
            for (int ni = 0; ni < 4; ++ni)
                bf[ni] = *(const bf16x8*)&lds[8192 + (wc * 64 + ni * 16 + l15) * 64 + cofs];
#pragma unroll
            for (int mi = 0; mi < 4; ++mi)
#pragma unroll
                for (int ni = 0; ni < 4; ++ni)
                    acc[mi][ni] = __builtin_amdgcn_mfma_f32_16x16x32_bf16(
                        af[mi], bf[ni], acc[mi][ni], 0, 0, 0);
#pragma unroll
            for (int ni = 0; ni < 4; ++ni)
                bf[ni] = *(const bf16x8*)&lds[16384 + (wc * 64 + ni * 16 + l15) * 64 + cofs];
#pragma unroll
            for (int mi = 0; mi < 4; ++mi)
#pragma unroll
                for (int ni = 0; ni < 4; ++ni)
                    acc[mi][ni] = __builtin_amdgcn_mfma_f32_16x16x32_bf16(
                        af[mi], bf[ni], acc[mi][ni], 0, 0, 0);
        }
    }
    // pass 2: acc += lo·ehi
    for (int kr = 0; kr < 4; ++kr) {
        __syncthreads();
        STAGE4(A2, row0, 256 + kr * 64, 0);
        STAGE4(B2, col0, kr * 64, 16384);
        asm volatile("s_waitcnt vmcnt(0)" ::: "memory");
        __syncthreads();
#pragma unroll
        for (int kk = 0; kk < 2; ++kk) {
            const int cofs = (kk * 32 + lhi * 8) ^ swz;
            bf16x8 af[4], bf[4];
#pragma unroll
            for (int mi = 0; mi < 4; ++mi)
                af[mi] = *(const bf16x8*)&lds[(wr * 64 + mi * 16 + l15) * 64 + cofs];
#pragma unroll
            for (int ni = 0; ni < 4; ++ni)
                bf[ni] = *(const bf16x8*)&lds[8192 + (wc * 64 + ni * 16 + l15) * 64 + cofs];
#pragma unroll
            for (int mi = 0; mi < 4; ++mi)
#pragma unroll
                for (int ni = 0; ni < 4; ++ni)
                    acc[mi][ni] = __builtin_amdgcn_mfma_f32_16x16x32_bf16(
                        af[mi], bf[ni], acc[mi][ni], 0, 0, 0);
        }
    }
#undef STAGE4

    // epilogue: per-row top-2 (values AND indices) over this wave's 64 cols
    float nv[4];
#pragma unroll
    for (int ni = 0; ni < 4; ++ni) nv[ni] = nrm[col0 + wc * 64 + ni * 16 + l15];
#pragma unroll
    for (int mi = 0; mi < 4; ++mi)
#pragma unroll
        for (int j = 0; j < 4; ++j) {
            float a = 3.4e38f, b = 3.4e38f; int ia = 0, ib = 0;
#pragma unroll
            for (int ni = 0; ni < 4; ++ni) {
                float dist = fmaf(-2.f, acc[mi][ni][j], nv[ni]);
                int col = col0 + wc * 64 + ni * 16 + l15;
                if (dist < a) { b = a; ib = ia; a = dist; ia = col; }
                else if (dist < b) { b = dist; ib = col; }
            }
#pragma unroll
            for (int off = 1; off < 16; off <<= 1) {
                float oa = __shfl_xor(a, off), ob = __shfl_xor(b, off);
                int   oi = __shfl_xor(ia, off), oj = __shfl_xor(ib, off);
                if (oa < a || (oa == a && oi < ia)) {
                    // other's best wins; second = better of (a,ia) vs (ob,oj)
                    if (a < ob || (a == ob && ia < oj)) { b = a; ib = ia; }
                    else { b = ob; ib = oj; }
                    a = oa; ia = oi;
                } else {
                    if (oa < b || (oa == b && oi < ib)) { b = oa; ib = oi; }
                }
            }
            if (l15 == 0) {
                int grow = row0 + wr * 64 + mi * 16 + lhi * 4 + j;
                float4 pv;
                pv.x = a; pv.y = __int_as_float(ia);
                pv.z = b; pv.w = __int_as_float(ib);
                pmin[(size_t)grow * 16 + cb * 2 + wc] = pv;
            }
        }
}

// ---------------------------------------------------------------------------
// merge 16 partials/row -> idxi; flagged rows get an explicit candidate set
// (all codes with gemm-dist < a+TAU). Hidden-code safety: slot.v2 >= a+TAU.
__global__ __launch_bounds__(256)
void vq_combine(float* __restrict__ out) {
    const float4* pmin = (const float4*)(out + PMIN_OFF);
    int* idxi = (int*)(out + IDXI_OFF);
    int* amb  = (int*)(out + AMB_OFF);
    int* fb   = (int*)(out + PART_OFF);
    const int row = blockIdx.x * 256 + threadIdx.x;
    float v1[16], v2[16]; int i1[16], i2[16];
    float a = 3.4e38f, b = 3.4e38f; int ia = 0;
#pragma unroll
    for (int s = 0; s < 16; ++s) {
        float4 p = pmin[(size_t)row * 16 + s];
        v1[s] = p.x; i1[s] = __float_as_int(p.y);
        v2[s] = p.z; i2[s] = __float_as_int(p.w);
        if (v1[s] < a || (v1[s] == a && i1[s] < ia)) { b = fminf(a, v2[s]); a = v1[s]; ia = i1[s]; }
        else b = fminf(b, v1[s]);
    }
    idxi[row] = ia;
    if (b - a < TAU) {
        const float lim = a + TAU;
        int cands[6]; int nc = 0; bool ok = true;
#pragma unroll
        for (int s = 0; s < 16; ++s) {
            if (v1[s] < lim) { if (nc < 6) cands[nc] = i1[s]; ++nc; }
            if (v2[s] < lim) { if (nc < 6) cands[nc] = i2[s]; ++nc; ok = false; }
            // v2[s]<lim means a 3rd (hidden) code in slot s could also be <lim
        }
        if (ok && nc <= 6) {
            int pos = atomicAdd(&amb[0], 1);
            if (pos < MAXCAND) {
                int* e = amb + 16 + pos * 8;
                e[0] = row; e[1] = nc;
#pragma unroll
                for (int c = 0; c < 6; ++c) e[2 + c] = (c < nc) ? cands[c] : 0;
            } else ok = false;
        } else ok = false;
        if (!ok) {
            int pos = atomicAdd(&amb[1], 1);
            if (pos < MAXFB) fb[pos] = row;
        }
    }
}

// ---------------------------------------------------------------------------
// candidate rescore: one THREAD per flagged row; f32-chain (bit-exact round-2
// arithmetic: fmaf d=0..255 via ET values, dist=fmaf(-2,acc,nrm), lowest-code
// tie-break) over its <=6 candidates only.
__global__ __launch_bounds__(256)
void vq_rescore_cand(const float* __restrict__ X, float* __restrict__ out) {
    const float* ET  = out + ET_OFF;
    const float* nrm = out + NRM_OFF;
    const int* amb = (const int*)(out + AMB_OFF);
    int* idxi = (int*)(out + IDXI_OFF);
    int count = amb[0]; if (count > MAXCAND) count = MAXCAND;
    for (int it = blockIdx.x * 256 + threadIdx.x; it < count; it += gridDim.x * 256) {
        const int* e = amb + 16 + it * 8;
        const int row = e[0], nc = e[1];
        const float* xp = X + (size_t)row * DIM;
        float best = 3.4e38f; int bi = 0x7fffffff;
        for (int c = 0; c < nc; ++c) {
            const int code = e[2 + c];
            const float* ep = ET + (size_t)code * DIM;
            float acc = 0.f;
#pragma unroll 8
            for (int d = 0; d < 256; ++d)
                acc = fmaf(xp[d], ep[d], acc);
            float dist = fmaf(-2.f, acc, nrm[code]);
            if (dist < best || (dist == best && code < bi)) { best = dist; bi = code; }
        }
        idxi[row] = bi;
    }
}

// ---------------------------------------------------------------------------
// fallback full scan (rare rows): one WAVE per row over all 1024 codes,
// same bit-exact chain (validated r7).
__global__ __launch_bounds__(256)
void vq_rescore_fb(const float* __restrict__ X, float* __restrict__ out) {
    __shared__ float xs[4][256];
    const float* ET  = out + ET_OFF;
    const float* nrm = out + NRM_OFF;
    const int* amb = (const int*)(out + AMB_OFF);
    const int* fb  = (const int*)(out + PART_OFF);
    int* idxi = (int*)(out + IDXI_OFF);
    const int wid = threadIdx.x >> 6, lane = threadIdx.x & 63;
    int count = amb[1]; if (count > MAXFB) count = MAXFB;
    for (int it = blockIdx.x * 4 + wid; it < count; it += gridDim.x * 4) {
        const int row = fb[it];
        *(float4*)&xs[wid][lane * 4] = *(const float4*)(X + (size_t)row * DIM + lane * 4);
        float best = 3.4e38f; int bi = 0;
        for (int cc = 0; cc < 16; ++cc) {
            const int code = cc * 64 + lane;
            const float* ep = ET + (size_t)code * DIM;
            float acc = 0.f;
#pragma unroll
            for (int d = 0; d < 256; d += 4) {
                float4 ev = *(const float4*)(ep + d);
                acc = fmaf(xs[wid][d],     ev.x, acc);
                acc = fmaf(xs[wid][d + 1], ev.y, acc);
                acc = fmaf(xs[wid][d + 2], ev.z, acc);
                acc = fmaf(xs[wid][d + 3], ev.w, acc);
            }
            float dist = fmaf(-2.f, acc, nrm[code]);
            if (dist < best) { best = dist; bi = code; }
        }
#pragma unroll
        for (int off = 1; off < 64; off <<= 1) {
            float ov = __shfl_xor(best, off);
            int   oi = __shfl_xor(bi, off);
            if (ov < best || (ov == best && oi < bi)) { best = ov; bi = oi; }
        }
        if (lane == 0) idxi[row] = bi;
    }
}

// ---------------------------------------------------------------------------
// outputs: quantized_st (gather from E^T), indices-as-float, loss partials
__global__ __launch_bounds__(256)
void vq_outputs(const float* __restrict__ X, float* __restrict__ out) {
    const float* ET  = out + ET_OFF;
    const int*   idx = (const int*)(out + IDXI_OFF);
    float*       part = out + PART_OFF;
    __shared__ float red[4];
    const int row  = blockIdx.x * 4 + (threadIdx.x >> 6);
    const int lane = threadIdx.x & 63;
    const int id   = idx[row];
    float4 e = *(const float4*)(ET + (size_t)id * DIM + lane * 4);
    float4 x = *(const float4*)(X + (size_t)row * DIM + lane * 4);
    float dx = e.x - x.x, dy = e.y - x.y, dz = e.z - x.z, dw = e.w - x.w;
    float4 q;
    q.x = x.x + dx; q.y = x.y + dy; q.z = x.z + dz; q.w = x.w + dw;
    *(float4*)(out + Q_OFF + (size_t)row * DIM + lane * 4) = q;
    float s = dx * dx + dy * dy + dz * dz + dw * dw;
#pragma unroll
    for (int off = 32; off >= 1; off >>= 1) s += __shfl_xor(s, off);
    if (lane == 0) {
        red[threadIdx.x >> 6] = s;
        out[IDX_OFF + row] = (float)id;
    }
    __syncthreads();
    if (threadIdx.x == 0) part[blockIdx.x] = red[0] + red[1] + red[2] + red[3];
}

// ---------------------------------------------------------------------------
__global__ __launch_bounds__(256)
void vq_loss(float* __restrict__ out) {
    const float* part = out + PART_OFF;
    __shared__ double red[256];
    const int tid = threadIdx.x;
    double s = 0.0;
    for (int i = tid; i < 16384; i += 256) s += (double)part[i];
    red[tid] = s;
    __syncthreads();
    for (int off = 128; off > 0; off >>= 1) {
        if (tid < off) red[tid] += red[tid + off];
        __syncthreads();
    }
    if (tid == 0)
        out[LOSS_OFF] = (float)(1.25 * red[0] / (double)((size_t)N_ROWS * DIM));
}

// ---------------------------------------------------------------------------
__global__ __launch_bounds__(256)
void vq_encodings(float* __restrict__ out) {
    const float* idxf = out + IDX_OFF;
    float4* enc4 = (float4*)(out + ENC_OFF);
    const size_t total4 = (size_t)N_ROWS * KCB / 4;
    const size_t stride = (size_t)gridDim.x * blockDim.x;
    for (size_t g = (size_t)blockIdx.x * blockDim.x + threadIdx.x; g < total4; g += stride) {
        int n  = (int)(g >> 8);
        int c0 = ((int)g & 255) * 4;
        int r  = (int)idxf[n] - c0;
        float4 v;
        v.x = (r == 0) ? 1.f : 0.f;
        v.y = (r == 1) ? 1.f : 0.f;
        v.z = (r == 2) ? 1.f : 0.f;
        v.w = (r == 3) ? 1.f : 0.f;
        enc4[g] = v;
    }
}

// ---------------------------------------------------------------------------
extern "C" void kernel_launch(void* const* d_in, const int* in_sizes, int n_in,
                              void* d_out, int out_size, void* d_ws, size_t ws_size,
                              hipStream_t stream) {
    const float* X = (const float*)d_in[0];   // [16,4096,256] f32
    const float* E = (const float*)d_in[1];   // [256,1024] f32
    float* out = (float*)d_out;

    vq_prep_a      <<<8192, 256, 0, stream>>>(X, out);
    vq_prep_b      <<<1024,  64, 0, stream>>>(E, out);
    vq_gemm        <<<4096, 256, 0, stream>>>(out);
    vq_combine     <<<256,  256, 0, stream>>>(out);
    vq_rescore_cand<<<64,   256, 0, stream>>>(X, out);
    vq_rescore_fb  <<<128,  256, 0, stream>>>(X, out);
    vq_outputs     <<<16384, 256, 0, stream>>>(X, out);
    vq_loss        <<<1,    256, 0, stream>>>(out);
    vq_encodings   <<<2048, 256, 0, stream>>>(out);
}

// Round 10
// 733.550 us; speedup vs baseline: 1.0302x; 1.0302x over previous
//
#include <hip/hip_runtime.h>

#define N_ROWS 65536          // 16*4096
#define DIM    256
#define KCB    1024

// d_out layout (floats), in reference return order
#define Q_OFF    0
#define ENC_OFF  (N_ROWS * DIM)                  // 16777216
#define IDX_OFF  (ENC_OFF + N_ROWS * KCB)        // 83886080
#define LOSS_OFF (IDX_OFF + N_ROWS)              // 83951616

// scratch carved out of the encodings region (overwritten by final kernel)
#define ET_OFF   (ENC_OFF + 0)                   // 262144 f32: E^T
#define NRM_OFF  (ENC_OFF + 262144)              // 1024 f32: ||e||^2
#define IDXI_OFF (ENC_OFF + 263168)              // 65536 int: final argmin
#define PART_OFF (ENC_OFF + 328704)              // 16384 f32: fb list / loss partials
#define AMB_OFF  (ENC_OFF + 345088)              // [0]=cand cnt [1]=fb cnt; entries @+16
#define PMIN_OFF (ENC_OFF + 524288)              // 65536*16 float4 partial minima
#define A2_OFF   (ENC_OFF + 4718592)             // bf16 [65536][512] {hi|lo}
#define BST_OFF  (ENC_OFF + 21495808)            // bf16 [1024][512] {ehi|elo}

#define TAU 0.05f        // validated r6/r7; flags rows AND bounds candidate set
#define MAXCAND 20000
#define MAXFB   16000

typedef short  bf16x8 __attribute__((ext_vector_type(8)));
typedef float  f32x4  __attribute__((ext_vector_type(4)));
typedef unsigned short u16x8 __attribute__((ext_vector_type(8)));
#define AS1 __attribute__((address_space(1)))
#define AS3 __attribute__((address_space(3)))

__device__ inline unsigned short f2bf(float x) {
    unsigned u = __float_as_uint(x);
    return (unsigned short)((u + 0x7FFFu + ((u >> 16) & 1u)) >> 16);
}
__device__ inline float bf2f(unsigned short b) {
    return __uint_as_float(((unsigned)b) << 16);
}

// ---------------------------------------------------------------------------
// split X (f32) -> A2 [row][512] bf16: [0,256)=hi, [256,512)=lo
__global__ __launch_bounds__(256)
void vq_prep_a(const float* __restrict__ X, float* __restrict__ out) {
    unsigned short* A2 = (unsigned short*)(out + A2_OFF);
    int gid = blockIdx.x * 256 + threadIdx.x;
    int row = gid >> 5;
    int d0  = (gid & 31) * 8;
    const float* xp = X + (size_t)row * DIM + d0;
    float4 v0 = *(const float4*)xp;
    float4 v1 = *(const float4*)(xp + 4);
    float xv[8] = {v0.x, v0.y, v0.z, v0.w, v1.x, v1.y, v1.z, v1.w};
    u16x8 h, l;
#pragma unroll
    for (int i = 0; i < 8; ++i) {
        unsigned short hb = f2bf(xv[i]);
        h[i] = hb;
        l[i] = f2bf(xv[i] - bf2f(hb));
    }
    *(u16x8*)(A2 + (size_t)row * 512 + d0) = h;
    *(u16x8*)(A2 + (size_t)row * 512 + 256 + d0) = l;
}

// ---------------------------------------------------------------------------
// E -> ET [1024][256] f32, nrm [1024], B2 [1024][512] bf16 {hi|lo}
// nrm chain must stay identical to round-2 prep (rescore replicates bit-exact).
__global__ __launch_bounds__(64)
void vq_prep_b(const float* __restrict__ E, float* __restrict__ out) {
    float* ET  = out + ET_OFF;
    float* nrm = out + NRM_OFF;
    unsigned short* B2 = (unsigned short*)(out + BST_OFF);
    const int k = blockIdx.x, t = threadIdx.x;
    float v[4]; float s = 0.f;
    ushort4 hb, lb;
#pragma unroll
    for (int i = 0; i < 4; ++i) {
        float e = E[(size_t)(t * 4 + i) * KCB + k];
        v[i] = e; s += e * e;
        unsigned short h = f2bf(e);
        ((unsigned short*)&hb)[i] = h;
        ((unsigned short*)&lb)[i] = f2bf(e - bf2f(h));
    }
    *(float4*)(ET + (size_t)k * DIM + t * 4) = *(float4*)v;
    *(ushort4*)(B2 + (size_t)k * 512 + t * 4) = hb;
    *(ushort4*)(B2 + (size_t)k * 512 + 256 + t * 4) = lb;
#pragma unroll
    for (int off = 32; off >= 1; off >>= 1) s += __shfl_xor(s, off);
    if (t == 0) nrm[k] = s;
    if (k == 0 && t == 0) { int* a = (int*)(out + AMB_OFF); a[0] = 0; a[1] = 0; }
}

// ---------------------------------------------------------------------------
// MFMA distance GEMM (sim = x_hi.e_hi + x_hi.e_lo + x_lo.e_hi), 128x128 tile,
// XOR-swizzled LDS. Inner loop = r7 form: bh+bl fragments loaded UPFRONT so
// ds_read latency hides under the first MFMA group (r8's split serialized on
// the reused registers and regressed).
// Epilogue: per-row (best, idx, second-val) -> pmin[row][cb*2+wc].
__global__ __launch_bounds__(256, 3)
void vq_gemm(float* __restrict__ out) {
    __shared__ short lds[24576];   // A @0B, Bhi @16384B, Blo @32768B
    const unsigned short* A2 = (const unsigned short*)(out + A2_OFF);
    const unsigned short* B2 = (const unsigned short*)(out + BST_OFF);
    const float* nrm = out + NRM_OFF;
    float4* pmin = (float4*)(out + PMIN_OFF);

    const int orig = blockIdx.x;
    const int mapped = (orig & 7) * 512 + (orig >> 3);   // XCD-contiguous
    const int rb = mapped >> 3, cb = mapped & 7;
    const int row0 = rb * 128, col0 = cb * 128;

    const int tid = threadIdx.x;
    const int lane = tid & 63, l15 = lane & 15, lhi = lane >> 4;
    const int w = tid >> 6, wr = w >> 1, wc = w & 1;
    const int swz = (l15 & 7) * 8;          // read-side XOR (shorts)

    f32x4 acc[4][4];
#pragma unroll
    for (int i = 0; i < 4; ++i)
#pragma unroll
        for (int j = 0; j < 4; ++j) acc[i][j] = (f32x4){0.f, 0.f, 0.f, 0.f};

    const int sr   = tid >> 3;
    const int sksw = ((tid & 7) ^ ((tid >> 3) & 7)) * 8;   // swizzled src col
    const int wofs = (tid & 192) * 16;

#define STAGE4(SRC, R0, KOFF, LDSB)                                           \
    _Pragma("unroll")                                                         \
    for (int i = 0; i < 4; ++i) {                                             \
        __builtin_amdgcn_global_load_lds(                                     \
            (const AS1 unsigned*)((SRC) + (size_t)((R0) + i * 32 + sr) * 512  \
                                  + (KOFF) + sksw),                           \
            (AS3 unsigned*)((char*)lds + (LDSB) + i * 4096 + wofs), 16, 0, 0);\
    }

    // pass 1: acc += hi·ehi + hi·elo (32 MFMA per barrier-pair, af reused)
    for (int kr = 0; kr < 4; ++kr) {
        __syncthreads();
        STAGE4(A2, row0, kr * 64, 0);
        STAGE4(B2, col0, kr * 64, 16384);
        STAGE4(B2, col0, 256 + kr * 64, 32768);
        asm volatile("s_waitcnt vmcnt(0)" ::: "memory");
        __syncthreads();
#pragma unroll
        for (int kk = 0; kk < 2; ++kk) {
            const int cofs = (kk * 32 + lhi * 8) ^ swz;
            bf16x8 af[4], bh[4], bl[4];
#pragma unroll
            for (int mi = 0; mi < 4; ++mi)
                af[mi] = *(const bf16x8*)&lds[(wr * 64 + mi * 16 + l15) * 64 + cofs];
#pragma unroll
            for (int ni = 0; ni < 4; ++ni) {
                bh[ni] = *(const bf16x8*)&lds[8192 + (wc * 64 + ni * 16 + l15) * 64 + cofs];
                bl[ni] = *(const bf16x8*)&lds[16384 + (wc * 64 + ni * 16 + l15) * 64 + cofs];
            }
#pragma unroll
            for (int mi = 0; mi < 4; ++mi)
#pragma unroll
                for (int ni = 0; ni < 4; ++ni)
                    acc[mi][ni] = __builtin_amdgcn_mfma_f32_16x16x32_bf16(
                        af[mi], bh[ni], acc[mi][ni], 0, 0, 0);
#pragma unroll
            for (int mi = 0; mi < 4; ++mi)
#pragma unroll
                for (int ni = 0; ni < 4; ++ni)
                    acc[mi][ni] = __builtin_amdgcn_mfma_f32_16x16x32_bf16(
                        af[mi], bl[ni], acc[mi][ni], 0, 0, 0);
        }
    }
    // pass 2: acc += lo·ehi
    for (int kr = 0; kr < 4; ++kr) {
        __syncthreads();
        STAGE4(A2, row0, 256 + kr * 64, 0);
        STAGE4(B2, col0, kr * 64, 16384);
        asm volatile("s_waitcnt vmcnt(0)" ::: "memory");
        __syncthreads();
#pragma unroll
        for (int kk = 0; kk < 2; ++kk) {
            const int cofs = (kk * 32 + lhi * 8) ^ swz;
            bf16x8 af[4], bh[4];
#pragma unroll
            for (int mi = 0; mi < 4; ++mi)
                af[mi] = *(const bf16x8*)&lds[(wr * 64 + mi * 16 + l15) * 64 + cofs];
#pragma unroll
            for (int ni = 0; ni < 4; ++ni)
                bh[ni] = *(const bf16x8*)&lds[8192 + (wc * 64 + ni * 16 + l15) * 64 + cofs];
#pragma unroll
            for (int mi = 0; mi < 4; ++mi)
#pragma unroll
                for (int ni = 0; ni < 4; ++ni)
                    acc[mi][ni] = __builtin_amdgcn_mfma_f32_16x16x32_bf16(
                        af[mi], bh[ni], acc[mi][ni], 0, 0, 0);
        }
    }
#undef STAGE4

    // epilogue: per-row (best value+index, second value) over wave's 64 cols
    float nv[4];
#pragma unroll
    for (int ni = 0; ni < 4; ++ni) nv[ni] = nrm[col0 + wc * 64 + ni * 16 + l15];
#pragma unroll
    for (int mi = 0; mi < 4; ++mi)
#pragma unroll
        for (int j = 0; j < 4; ++j) {
            float a = 3.4e38f, b = 3.4e38f; int ia = 0;
#pragma unroll
            for (int ni = 0; ni < 4; ++ni) {
                float dist = fmaf(-2.f, acc[mi][ni][j], nv[ni]);
                int col = col0 + wc * 64 + ni * 16 + l15;
                if (dist < a) { b = a; a = dist; ia = col; }
                else if (dist < b) b = dist;
            }
#pragma unroll
            for (int off = 1; off < 16; off <<= 1) {
                float oa = __shfl_xor(a, off);
                float ob = __shfl_xor(b, off);
                int   oi = __shfl_xor(ia, off);
                if (oa < a || (oa == a && oi < ia)) { b = fminf(a, ob); a = oa; ia = oi; }
                else b = fminf(b, oa);
            }
            if (l15 == 0) {
                int grow = row0 + wr * 64 + mi * 16 + lhi * 4 + j;
                float4 pv;
                pv.x = a; pv.y = __int_as_float(ia); pv.z = b; pv.w = 0.f;
                pmin[(size_t)grow * 16 + cb * 2 + wc] = pv;
            }
        }
}

// ---------------------------------------------------------------------------
// merge 16 partials/row (streaming, low VGPR) -> idxi; flagged rows: second
// pass over pmin collects candidates {codes with v1 < a+TAU}. Any slot whose
// v2 < lim may hide a 3rd candidate -> fallback full scan.
__global__ __launch_bounds__(256)
void vq_combine(float* __restrict__ out) {
    const float4* pmin = (const float4*)(out + PMIN_OFF);
    int* idxi = (int*)(out + IDXI_OFF);
    int* amb  = (int*)(out + AMB_OFF);
    int* fb   = (int*)(out + PART_OFF);
    const int row = blockIdx.x * 256 + threadIdx.x;
    float a = 3.4e38f, b = 3.4e38f; int ia = 0;
#pragma unroll
    for (int s = 0; s < 16; ++s) {
        float4 p = pmin[(size_t)row * 16 + s];
        float v1 = p.x; int i1 = __float_as_int(p.y);
        if (v1 < a || (v1 == a && i1 < ia)) { b = fminf(a, p.z); a = v1; ia = i1; }
        else b = fminf(b, v1);
    }
    idxi[row] = ia;
    if (b - a < TAU) {
        const float lim = a + TAU;
        int cands[6]; int nc = 0; bool ok = true;
#pragma unroll
        for (int s = 0; s < 16; ++s) {
            float4 p = pmin[(size_t)row * 16 + s];
            if (p.z < lim) ok = false;            // hidden 3rd code possible
            if (p.x < lim) { if (nc < 6) cands[nc] = __float_as_int(p.y); ++nc; }
        }
        if (ok && nc <= 6) {
            int pos = atomicAdd(&amb[0], 1);
            if (pos < MAXCAND) {
                int* e = amb + 16 + pos * 8;
                e[0] = row; e[1] = nc;
#pragma unroll
                for (int c = 0; c < 6; ++c) e[2 + c] = (c < nc) ? cands[c] : 0;
            } else ok = false;
        } else ok = false;
        if (!ok) {
            int pos = atomicAdd(&amb[1], 1);
            if (pos < MAXFB) fb[pos] = row;
        }
    }
}

// ---------------------------------------------------------------------------
// candidate rescore: one THREAD per flagged row; bit-exact round-2 f32 chain
// (fmaf d=0..255 via ET, dist=fmaf(-2,acc,nrm), lowest-code tie-break).
__global__ __launch_bounds__(256)
void vq_rescore_cand(const float* __restrict__ X, float* __restrict__ out) {
    const float* ET  = out + ET_OFF;
    const float* nrm = out + NRM_OFF;
    const int* amb = (const int*)(out + AMB_OFF);
    int* idxi = (int*)(out + IDXI_OFF);
    int count = amb[0]; if (count > MAXCAND) count = MAXCAND;
    for (int it = blockIdx.x * 256 + threadIdx.x; it < count; it += gridDim.x * 256) {
        const int* e = amb + 16 + it * 8;
        const int row = e[0], nc = e[1];
        const float* xp = X + (size_t)row * DIM;
        float best = 3.4e38f; int bi = 0x7fffffff;
        for (int c = 0; c < nc; ++c) {
            const int code = e[2 + c];
            const float* ep = ET + (size_t)code * DIM;
            float acc = 0.f;
#pragma unroll 8
            for (int d = 0; d < 256; ++d)
                acc = fmaf(xp[d], ep[d], acc);
            float dist = fmaf(-2.f, acc, nrm[code]);
            if (dist < best || (dist == best && code < bi)) { best = dist; bi = code; }
        }
        idxi[row] = bi;
    }
}

// ---------------------------------------------------------------------------
// fallback full scan (rare rows): one WAVE per row, same bit-exact chain.
__global__ __launch_bounds__(256)
void vq_rescore_fb(const float* __restrict__ X, float* __restrict__ out) {
    __shared__ float xs[4][256];
    const float* ET  = out + ET_OFF;
    const float* nrm = out + NRM_OFF;
    const int* amb = (const int*)(out + AMB_OFF);
    const int* fb  = (const int*)(out + PART_OFF);
    int* idxi = (int*)(out + IDXI_OFF);
    const int wid = threadIdx.x >> 6, lane = threadIdx.x & 63;
    int count = amb[1]; if (count > MAXFB) count = MAXFB;
    for (int it = blockIdx.x * 4 + wid; it < count; it += gridDim.x * 4) {
        const int row = fb[it];
        *(float4*)&xs[wid][lane * 4] = *(const float4*)(X + (size_t)row * DIM + lane * 4);
        float best = 3.4e38f; int bi = 0;
        for (int cc = 0; cc < 16; ++cc) {
            const int code = cc * 64 + lane;
            const float* ep = ET + (size_t)code * DIM;
            float acc = 0.f;
#pragma unroll
            for (int d = 0; d < 256; d += 4) {
                float4 ev = *(const float4*)(ep + d);
                acc = fmaf(xs[wid][d],     ev.x, acc);
                acc = fmaf(xs[wid][d + 1], ev.y, acc);
                acc = fmaf(xs[wid][d + 2], ev.z, acc);
                acc = fmaf(xs[wid][d + 3], ev.w, acc);
            }
            float dist = fmaf(-2.f, acc, nrm[code]);
            if (dist < best) { best = dist; bi = code; }
        }
#pragma unroll
        for (int off = 1; off < 64; off <<= 1) {
            float ov = __shfl_xor(best, off);
            int   oi = __shfl_xor(bi, off);
            if (ov < best || (ov == best && oi < bi)) { best = ov; bi = oi; }
        }
        if (lane == 0) idxi[row] = bi;
    }
}

// ---------------------------------------------------------------------------
// outputs: quantized_st (gather from E^T), indices-as-float, loss partials
__global__ __launch_bounds__(256)
void vq_outputs(const float* __restrict__ X, float* __restrict__ out) {
    const float* ET  = out + ET_OFF;
    const int*   idx = (const int*)(out + IDXI_OFF);
    float*       part = out + PART_OFF;
    __shared__ float red[4];
    const int row  = blockIdx.x * 4 + (threadIdx.x >> 6);
    const int lane = threadIdx.x & 63;
    const int id   = idx[row];
    float4 e = *(const float4*)(ET + (size_t)id * DIM + lane * 4);
    float4 x = *(const float4*)(X + (size_t)row * DIM + lane * 4);
    float dx = e.x - x.x, dy = e.y - x.y, dz = e.z - x.z, dw = e.w - x.w;
    float4 q;
    q.x = x.x + dx; q.y = x.y + dy; q.z = x.z + dz; q.w = x.w + dw;
    *(float4*)(out + Q_OFF + (size_t)row * DIM + lane * 4) = q;
    float s = dx * dx + dy * dy + dz * dz + dw * dw;
#pragma unroll
    for (int off = 32; off >= 1; off >>= 1) s += __shfl_xor(s, off);
    if (lane == 0) {
        red[threadIdx.x >> 6] = s;
        out[IDX_OFF + row] = (float)id;
    }
    __syncthreads();
    if (threadIdx.x == 0) part[blockIdx.x] = red[0] + red[1] + red[2] + red[3];
}

// ---------------------------------------------------------------------------
__global__ __launch_bounds__(256)
void vq_loss(float* __restrict__ out) {
    const float* part = out + PART_OFF;
    __shared__ double red[256];
    const int tid = threadIdx.x;
    double s = 0.0;
    for (int i = tid; i < 16384; i += 256) s += (double)part[i];
    red[tid] = s;
    __syncthreads();
    for (int off = 128; off > 0; off >>= 1) {
        if (tid < off) red[tid] += red[tid + off];
        __syncthreads();
    }
    if (tid == 0)
        out[LOSS_OFF] = (float)(1.25 * red[0] / (double)((size_t)N_ROWS * DIM));
}

// ---------------------------------------------------------------------------
__global__ __launch_bounds__(256)
void vq_encodings(float* __restrict__ out) {
    const float* idxf = out + IDX_OFF;
    float4* enc4 = (float4*)(out + ENC_OFF);
    const size_t total4 = (size_t)N_ROWS * KCB / 4;
    const size_t stride = (size_t)gridDim.x * blockDim.x;
    for (size_t g = (size_t)blockIdx.x * blockDim.x + threadIdx.x; g < total4; g += stride) {
        int n  = (int)(g >> 8);
        int c0 = ((int)g & 255) * 4;
        int r  = (int)idxf[n] - c0;
        float4 v;
        v.x = (r == 0) ? 1.f : 0.f;
        v.y = (r == 1) ? 1.f : 0.f;
        v.z = (r == 2) ? 1.f : 0.f;
        v.w = (r == 3) ? 1.f : 0.f;
        enc4[g] = v;
    }
}

// ---------------------------------------------------------------------------
extern "C" void kernel_launch(void* const* d_in, const int* in_sizes, int n_in,
                              void* d_out, int out_size, void* d_ws, size_t ws_size,
                              hipStream_t stream) {
    const float* X = (const float*)d_in[0];   // [16,4096,256] f32
    const float* E = (const float*)d_in[1];   // [256,1024] f32
    float* out = (float*)d_out;

    vq_prep_a      <<<8192, 256, 0, stream>>>(X, out);
    vq_prep_b      <<<1024,  64, 0, stream>>>(E, out);
    vq_gemm        <<<4096, 256, 0, stream>>>(out);
    vq_combine     <<<256,  256, 0, stream>>>(out);
    vq_rescore_cand<<<256,  256, 0, stream>>>(X, out);
    vq_rescore_fb  <<<128,  256, 0, stream>>>(X, out);
    vq_outputs     <<<16384, 256, 0, stream>>>(X, out);
    vq_loss        <<<1,    256, 0, stream>>>(out);
    vq_encodings   <<<2048, 256, 0, stream>>>(out);
}

// Round 11
// 677.115 us; speedup vs baseline: 1.1160x; 1.0833x over previous
//
#include <hip/hip_runtime.h>

#define N_ROWS 65536          // 16*4096
#define DIM    256
#define KCB    1024

// d_out layout (floats), in reference return order
#define Q_OFF    0
#define ENC_OFF  (N_ROWS * DIM)                  // 16777216
#define IDX_OFF  (ENC_OFF + N_ROWS * KCB)        // 83886080
#define LOSS_OFF (IDX_OFF + N_ROWS)              // 83951616

// scratch carved out of the encodings region (overwritten by final kernel)
#define ET_OFF   (ENC_OFF + 0)                   // 262144 f32: E^T
#define NRM_OFF  (ENC_OFF + 262144)              // 1024 f32: ||e||^2
#define IDXI_OFF (ENC_OFF + 263168)              // 65536 int: final argmin
#define PART_OFF (ENC_OFF + 328704)              // 16384 f32: loss partials
#define PMIN_OFF (ENC_OFF + 524288)              // 65536*16 float4 partial minima
#define A2_OFF   (ENC_OFF + 4718592)             // bf16 [65536][512] {hi|lo}
#define BST_OFF  (ENC_OFF + 21495808)            // bf16 [1024][512] {ehi|elo}

#define TAU 0.05f        // validated r6-r10; flags rows AND bounds candidate set

typedef short  bf16x8 __attribute__((ext_vector_type(8)));
typedef float  f32x4  __attribute__((ext_vector_type(4)));
typedef unsigned short u16x8 __attribute__((ext_vector_type(8)));
#define AS1 __attribute__((address_space(1)))
#define AS3 __attribute__((address_space(3)))

__device__ inline unsigned short f2bf(float x) {
    unsigned u = __float_as_uint(x);
    return (unsigned short)((u + 0x7FFFu + ((u >> 16) & 1u)) >> 16);
}
__device__ inline float bf2f(unsigned short b) {
    return __uint_as_float(((unsigned)b) << 16);
}

// ---------------------------------------------------------------------------
// fused prep: blocks [0,8192) split X -> A2 {hi|lo}; blocks [8192,9216) build
// ET / nrm / B2. nrm chain identical to round-2 (resolve replicates bit-exact).
__global__ __launch_bounds__(256)
void vq_prep(const float* __restrict__ X, const float* __restrict__ E,
             float* __restrict__ out) {
    if (blockIdx.x < 8192) {
        unsigned short* A2 = (unsigned short*)(out + A2_OFF);
        int gid = blockIdx.x * 256 + threadIdx.x;
        int row = gid >> 5;
        int d0  = (gid & 31) * 8;
        const float* xp = X + (size_t)row * DIM + d0;
        float4 v0 = *(const float4*)xp;
        float4 v1 = *(const float4*)(xp + 4);
        float xv[8] = {v0.x, v0.y, v0.z, v0.w, v1.x, v1.y, v1.z, v1.w};
        u16x8 h, l;
#pragma unroll
        for (int i = 0; i < 8; ++i) {
            unsigned short hb = f2bf(xv[i]);
            h[i] = hb;
            l[i] = f2bf(xv[i] - bf2f(hb));
        }
        *(u16x8*)(A2 + (size_t)row * 512 + d0) = h;
        *(u16x8*)(A2 + (size_t)row * 512 + 256 + d0) = l;
    } else {
        const int k = blockIdx.x - 8192, t = threadIdx.x;
        if (t < 64) {
            float* ET  = out + ET_OFF;
            float* nrm = out + NRM_OFF;
            unsigned short* B2 = (unsigned short*)(out + BST_OFF);
            float v[4]; float s = 0.f;
            ushort4 hb, lb;
#pragma unroll
            for (int i = 0; i < 4; ++i) {
                float e = E[(size_t)(t * 4 + i) * KCB + k];
                v[i] = e; s += e * e;
                unsigned short h = f2bf(e);
                ((unsigned short*)&hb)[i] = h;
                ((unsigned short*)&lb)[i] = f2bf(e - bf2f(h));
            }
            *(float4*)(ET + (size_t)k * DIM + t * 4) = *(float4*)v;
            *(ushort4*)(B2 + (size_t)k * 512 + t * 4) = hb;
            *(ushort4*)(B2 + (size_t)k * 512 + 256 + t * 4) = lb;
#pragma unroll
            for (int off = 32; off >= 1; off >>= 1) s += __shfl_xor(s, off);
            if (t == 0) nrm[k] = s;
        }
    }
}

// ---------------------------------------------------------------------------
// MFMA distance GEMM (sim = x_hi.e_hi + x_hi.e_lo + x_lo.e_hi), 128x128 tile,
// XOR-swizzled LDS, r10 structure (known-passing).
// Epilogue: per-row (best, idx, second-val) -> pmin[row][cb*2+wc].
__global__ __launch_bounds__(256, 3)
void vq_gemm(float* __restrict__ out) {
    __shared__ short lds[24576];   // A @0B, Bhi @16384B, Blo @32768B
    const unsigned short* A2 = (const unsigned short*)(out + A2_OFF);
    const unsigned short* B2 = (const unsigned short*)(out + BST_OFF);
    const float* nrm = out + NRM_OFF;
    float4* pmin = (float4*)(out + PMIN_OFF);

    const int orig = blockIdx.x;
    const int mapped = (orig & 7) * 512 + (orig >> 3);   // XCD-contiguous
    const int rb = mapped >> 3, cb = mapped & 7;
    const int row0 = rb * 128, col0 = cb * 128;

    const int tid = threadIdx.x;
    const int lane = tid & 63, l15 = lane & 15, lhi = lane >> 4;
    const int w = tid >> 6, wr = w >> 1, wc = w & 1;
    const int swz = (l15 & 7) * 8;          // read-side XOR (shorts)

    f32x4 acc[4][4];
#pragma unroll
    for (int i = 0; i < 4; ++i)
#pragma unroll
        for (int j = 0; j < 4; ++j) acc[i][j] = (f32x4){0.f, 0.f, 0.f, 0.f};

    const int sr   = tid >> 3;
    const int sksw = ((tid & 7) ^ ((tid >> 3) & 7)) * 8;   // swizzled src col
    const int wofs = (tid & 192) * 16;

#define STAGE4(SRC, R0, KOFF, LDSB)                                           \
    _Pragma("unroll")                                                         \
    for (int i = 0; i < 4; ++i) {                                             \
        __builtin_amdgcn_global_load_lds(                                     \
            (const AS1 unsigned*)((SRC) + (size_t)((R0) + i * 32 + sr) * 512  \
                                  + (KOFF) + sksw),                           \
            (AS3 unsigned*)((char*)lds + (LDSB) + i * 4096 + wofs), 16, 0, 0);\
    }

    // pass 1: acc += hi·ehi + hi·elo (32 MFMA per barrier-pair, af reused)
    for (int kr = 0; kr < 4; ++kr) {
        __syncthreads();
        STAGE4(A2, row0, kr * 64, 0);
        STAGE4(B2, col0, kr * 64, 16384);
        STAGE4(B2, col0, 256 + kr * 64, 32768);
        asm volatile("s_waitcnt vmcnt(0)" ::: "memory");
        __syncthreads();
#pragma unroll
        for (int kk = 0; kk < 2; ++kk) {
            const int cofs = (kk * 32 + lhi * 8) ^ swz;
            bf16x8 af[4], bh[4], bl[4];
#pragma unroll
            for (int mi = 0; mi < 4; ++mi)
                af[mi] = *(const bf16x8*)&lds[(wr * 64 + mi * 16 + l15) * 64 + cofs];
#pragma unroll
            for (int ni = 0; ni < 4; ++ni) {
                bh[ni] = *(const bf16x8*)&lds[8192 + (wc * 64 + ni * 16 + l15) * 64 + cofs];
                bl[ni] = *(const bf16x8*)&lds[16384 + (wc * 64 + ni * 16 + l15) * 64 + cofs];
            }
#pragma unroll
            for (int mi = 0; mi < 4; ++mi)
#pragma unroll
                for (int ni = 0; ni < 4; ++ni)
                    acc[mi][ni] = __builtin_amdgcn_mfma_f32_16x16x32_bf16(
                        af[mi], bh[ni], acc[mi][ni], 0, 0, 0);
#pragma unroll
            for (int mi = 0; mi < 4; ++mi)
#pragma unroll
                for (int ni = 0; ni < 4; ++ni)
                    acc[mi][ni] = __builtin_amdgcn_mfma_f32_16x16x32_bf16(
                        af[mi], bl[ni], acc[mi][ni], 0, 0, 0);
        }
    }
    // pass 2: acc += lo·ehi
    for (int kr = 0; kr < 4; ++kr) {
        __syncthreads();
        STAGE4(A2, row0, 256 + kr * 64, 0);
        STAGE4(B2, col0, kr * 64, 16384);
        asm volatile("s_waitcnt vmcnt(0)" ::: "memory");
        __syncthreads();
#pragma unroll
        for (int kk = 0; kk < 2; ++kk) {
            const int cofs = (kk * 32 + lhi * 8) ^ swz;
            bf16x8 af[4], bh[4];
#pragma unroll
            for (int mi = 0; mi < 4; ++mi)
                af[mi] = *(const bf16x8*)&lds[(wr * 64 + mi * 16 + l15) * 64 + cofs];
#pragma unroll
            for (int ni = 0; ni < 4; ++ni)
                bh[ni] = *(const bf16x8*)&lds[8192 + (wc * 64 + ni * 16 + l15) * 64 + cofs];
#pragma unroll
            for (int mi = 0; mi < 4; ++mi)
#pragma unroll
                for (int ni = 0; ni < 4; ++ni)
                    acc[mi][ni] = __builtin_amdgcn_mfma_f32_16x16x32_bf16(
                        af[mi], bh[ni], acc[mi][ni], 0, 0, 0);
        }
    }
#undef STAGE4

    // epilogue: per-row (best value+index, second value) over wave's 64 cols
    float nv[4];
#pragma unroll
    for (int ni = 0; ni < 4; ++ni) nv[ni] = nrm[col0 + wc * 64 + ni * 16 + l15];
#pragma unroll
    for (int mi = 0; mi < 4; ++mi)
#pragma unroll
        for (int j = 0; j < 4; ++j) {
            float a = 3.4e38f, b = 3.4e38f; int ia = 0;
#pragma unroll
            for (int ni = 0; ni < 4; ++ni) {
                float dist = fmaf(-2.f, acc[mi][ni][j], nv[ni]);
                int col = col0 + wc * 64 + ni * 16 + l15;
                if (dist < a) { b = a; a = dist; ia = col; }
                else if (dist < b) b = dist;
            }
#pragma unroll
            for (int off = 1; off < 16; off <<= 1) {
                float oa = __shfl_xor(a, off);
                float ob = __shfl_xor(b, off);
                int   oi = __shfl_xor(ia, off);
                if (oa < a || (oa == a && oi < ia)) { b = fminf(a, ob); a = oa; ia = oi; }
                else b = fminf(b, oa);
            }
            if (l15 == 0) {
                int grow = row0 + wr * 64 + mi * 16 + lhi * 4 + j;
                float4 pv;
                pv.x = a; pv.y = __int_as_float(ia); pv.z = b; pv.w = 0.f;
                pmin[(size_t)grow * 16 + cb * 2 + wc] = pv;
            }
        }
}

// ---------------------------------------------------------------------------
// fused resolve: per-thread merge of 16 partials -> idxi; flagged rows get
// inline candidate rescore (bit-exact round-2 f32 chain: fmaf d=0..255 via ET,
// dist=fmaf(-2,acc,nrm), lowest-code tie-break). Rows whose candidate set may
// be incomplete (winning-slot v2 < lim) go to a BLOCK-LOCAL fallback list,
// processed after a barrier with one wave per row full-scan (r7-validated).
__global__ __launch_bounds__(256)
void vq_resolve(const float* __restrict__ X, float* __restrict__ out) {
    __shared__ int   fb_list[256];
    __shared__ int   fb_cnt;
    __shared__ float xs[4][256];
    const float4* pmin = (const float4*)(out + PMIN_OFF);
    const float*  ET   = out + ET_OFF;
    const float*  nrm  = out + NRM_OFF;
    int* idxi = (int*)(out + IDXI_OFF);
    const int tid = threadIdx.x;
    if (tid == 0) fb_cnt = 0;
    __syncthreads();

    const int row = blockIdx.x * 256 + tid;
    float a = 3.4e38f, b = 3.4e38f; int ia = 0;
#pragma unroll
    for (int s = 0; s < 16; ++s) {
        float4 p = pmin[(size_t)row * 16 + s];
        float v1 = p.x; int i1 = __float_as_int(p.y);
        if (v1 < a || (v1 == a && i1 < ia)) { b = fminf(a, p.z); a = v1; ia = i1; }
        else b = fminf(b, v1);
    }
    int result = ia;
    if (b - a < TAU) {
        const float lim = a + TAU;
        int cands[6]; int nc = 0; bool ok = true;
#pragma unroll
        for (int s = 0; s < 16; ++s) {
            float4 p = pmin[(size_t)row * 16 + s];
            if (p.z < lim) ok = false;            // hidden 3rd code possible
            if (p.x < lim) { if (nc < 6) cands[nc] = __float_as_int(p.y); ++nc; }
        }
        if (ok && nc <= 6) {
            // inline candidate rescore (typically nc==2)
            const float* xp = X + (size_t)row * DIM;
            float best = 3.4e38f; int bi = 0x7fffffff;
            for (int c = 0; c < nc; ++c) {
                const int code = cands[c];
                const float* ep = ET + (size_t)code * DIM;
                float acc = 0.f;
#pragma unroll 8
                for (int d = 0; d < 256; ++d)
                    acc = fmaf(xp[d], ep[d], acc);
                float dist = fmaf(-2.f, acc, nrm[code]);
                if (dist < best || (dist == best && code < bi)) { best = dist; bi = code; }
            }
            result = bi;
        } else {
            int pos = atomicAdd(&fb_cnt, 1);      // pos < 256 by construction
            fb_list[pos] = row;
        }
    }
    idxi[row] = result;
    __syncthreads();

    // fallback: one wave per row, full 1024-code scan, same bit-exact chain
    const int wid = tid >> 6, lane = tid & 63;
    const int fbc = fb_cnt;
    for (int i = wid; i < fbc; i += 4) {
        const int row2 = fb_list[i];
        *(float4*)&xs[wid][lane * 4] = *(const float4*)(X + (size_t)row2 * DIM + lane * 4);
        float best = 3.4e38f; int bi = 0;
        for (int cc = 0; cc < 16; ++cc) {
            const int code = cc * 64 + lane;
            const float* ep = ET + (size_t)code * DIM;
            float acc = 0.f;
#pragma unroll
            for (int d = 0; d < 256; d += 4) {
                float4 ev = *(const float4*)(ep + d);
                acc = fmaf(xs[wid][d],     ev.x, acc);
                acc = fmaf(xs[wid][d + 1], ev.y, acc);
                acc = fmaf(xs[wid][d + 2], ev.z, acc);
                acc = fmaf(xs[wid][d + 3], ev.w, acc);
            }
            float dist = fmaf(-2.f, acc, nrm[code]);
            if (dist < best) { best = dist; bi = code; }
        }
#pragma unroll
        for (int off = 1; off < 64; off <<= 1) {
            float ov = __shfl_xor(best, off);
            int   oi = __shfl_xor(bi, off);
            if (ov < best || (ov == best && oi < bi)) { best = ov; bi = oi; }
        }
        if (lane == 0) idxi[row2] = bi;
    }
}

// ---------------------------------------------------------------------------
// outputs: quantized_st (gather from E^T), indices-as-float, loss partials
__global__ __launch_bounds__(256)
void vq_outputs(const float* __restrict__ X, float* __restrict__ out) {
    const float* ET  = out + ET_OFF;
    const int*   idx = (const int*)(out + IDXI_OFF);
    float*       part = out + PART_OFF;
    __shared__ float red[4];
    const int row  = blockIdx.x * 4 + (threadIdx.x >> 6);
    const int lane = threadIdx.x & 63;
    const int id   = idx[row];
    float4 e = *(const float4*)(ET + (size_t)id * DIM + lane * 4);
    float4 x = *(const float4*)(X + (size_t)row * DIM + lane * 4);
    float dx = e.x - x.x, dy = e.y - x.y, dz = e.z - x.z, dw = e.w - x.w;
    float4 q;
    q.x = x.x + dx; q.y = x.y + dy; q.z = x.z + dz; q.w = x.w + dw;
    *(float4*)(out + Q_OFF + (size_t)row * DIM + lane * 4) = q;
    float s = dx * dx + dy * dy + dz * dz + dw * dw;
#pragma unroll
    for (int off = 32; off >= 1; off >>= 1) s += __shfl_xor(s, off);
    if (lane == 0) {
        red[threadIdx.x >> 6] = s;
        out[IDX_OFF + row] = (float)id;
    }
    __syncthreads();
    if (threadIdx.x == 0) part[blockIdx.x] = red[0] + red[1] + red[2] + red[3];
}

// ---------------------------------------------------------------------------
// fused encodings + loss: block 0 finalizes loss (f64 over the 16384 partials
// written by vq_outputs), then all blocks grid-stride the one-hot writes.
__global__ __launch_bounds__(256)
void vq_encloss(float* __restrict__ out) {
    if (blockIdx.x == 0) {
        const float* part = out + PART_OFF;
        __shared__ double red[256];
        const int tid = threadIdx.x;
        double s = 0.0;
        for (int i = tid; i < 16384; i += 256) s += (double)part[i];
        red[tid] = s;
        __syncthreads();
        for (int off = 128; off > 0; off >>= 1) {
            if (tid < off) red[tid] += red[tid + off];
            __syncthreads();
        }
        if (tid == 0)
            out[LOSS_OFF] = (float)(1.25 * red[0] / (double)((size_t)N_ROWS * DIM));
        __syncthreads();
    }
    const float* idxf = out + IDX_OFF;
    float4* enc4 = (float4*)(out + ENC_OFF);
    const size_t total4 = (size_t)N_ROWS * KCB / 4;
    const size_t stride = (size_t)gridDim.x * blockDim.x;
    for (size_t g = (size_t)blockIdx.x * blockDim.x + threadIdx.x; g < total4; g += stride) {
        int n  = (int)(g >> 8);
        int c0 = ((int)g & 255) * 4;
        int r  = (int)idxf[n] - c0;
        float4 v;
        v.x = (r == 0) ? 1.f : 0.f;
        v.y = (r == 1) ? 1.f : 0.f;
        v.z = (r == 2) ? 1.f : 0.f;
        v.w = (r == 3) ? 1.f : 0.f;
        enc4[g] = v;
    }
}

// ---------------------------------------------------------------------------
extern "C" void kernel_launch(void* const* d_in, const int* in_sizes, int n_in,
                              void* d_out, int out_size, void* d_ws, size_t ws_size,
                              hipStream_t stream) {
    const float* X = (const float*)d_in[0];   // [16,4096,256] f32
    const float* E = (const float*)d_in[1];   // [256,1024] f32
    float* out = (float*)d_out;

    vq_prep    <<<9216,  256, 0, stream>>>(X, E, out);
    vq_gemm    <<<4096,  256, 0, stream>>>(out);
    vq_resolve <<<256,   256, 0, stream>>>(X, out);
    vq_outputs <<<16384, 256, 0, stream>>>(X, out);
    vq_encloss <<<2048,  256, 0, stream>>>(out);
}